// Round 4
// baseline (264.014 us; speedup 1.0000x reference)
//
#include <hip/hip_runtime.h>
#include <hip/hip_bf16.h>

typedef short short8 __attribute__((ext_vector_type(8)));
typedef float f32x4 __attribute__((ext_vector_type(4)));
typedef unsigned short u16;

#define SCALE_C 0.17677669529663687f

__device__ __forceinline__ u16 f2b(float f) {
  union { float f; unsigned int u; } v; v.f = f;
  unsigned int u = v.u;
  return (u16)((u + 0x7FFFu + ((u >> 16) & 1u)) >> 16);
}
__device__ __forceinline__ float b2f(u16 b) {
  union { unsigned int u; float f; } v; v.u = ((unsigned int)b) << 16; return v.f;
}

__device__ __forceinline__ void glds16(const void* g, void* l) {
  __builtin_amdgcn_global_load_lds(
      (const __attribute__((address_space(1))) unsigned int*)g,
      (__attribute__((address_space(3))) unsigned int*)l, 16, 0, 0);
}

// ---------------- prep kernels ----------------
__global__ void prep0(const float* Wq, const float* Wk, const float* Wv, const float* Wo,
                      const float* bk, const float* bv,
                      u16* wqT, u16* wkvT, u16* woT, float* bkv) {
  int j = blockIdx.x, t = threadIdx.x;
  wqT[j * 256 + t] = f2b(Wq[t * 256 + j]);
  wkvT[j * 256 + t] = f2b(Wk[t * 256 + j]);
  wkvT[(256 + j) * 256 + t] = f2b(Wv[t * 256 + j]);
  woT[j * 256 + t] = f2b(Wo[t * 256 + j]);
  if (t == 0) { bkv[j] = bk[j]; bkv[256 + j] = bv[j]; }
}

__global__ void prep1(const float* Wt, const float* Wo, const float* bt, const float* bo,
                      float* wtloT, float* btlo) {
  __shared__ float woj[256];
  int j = blockIdx.x, c = threadIdx.x;
  woj[c] = Wo[c * 256 + j];
  __syncthreads();
  float s = 0.f;
  const float* wr = Wt + c * 256;
#pragma unroll 8
  for (int t = 0; t < 256; ++t) s += wr[t] * woj[t];
  wtloT[j * 256 + c] = s;  // = Wtlo[c][j]
  if (c == 0) {
    float b = bo[j];
    for (int t = 0; t < 256; ++t) b += bt[t] * woj[t];
    btlo[j] = b;
  }
}

__global__ void prep2(const float* pk, const float* wtloT, const u16* woT, u16* B5) {
  int n = blockIdx.x >> 8, j = blockIdx.x & 255, t = threadIdx.x;
  u16* r = B5 + ((size_t)(n * 256 + j)) * 512;
  r[t] = f2b(pk[n * 256 + t] * wtloT[j * 256 + t]);
  r[256 + t] = woT[j * 256 + t];
}

// ---------------- GEMM: reg-staged A (fused fp32->bf16), glds dbuf B ----------------
// 128x128 tile, 4 waves (2x2), BK=64. As single-buffered (16KB), Bs double (32KB).
// LDS 16B-granule XOR swizzle g^(row&7); B achieves it via pre-swizzled global src.
template <int KT, bool AF32, bool DUAL, bool OUTF, int NT>
__global__ __launch_bounds__(256) void gemm4(
    const float* Af, const u16* A0, const u16* A1, const u16* B, int ldb, long bstr,
    const float* bias, u16* out0, u16* out1, float* outf) {
  __shared__ __align__(16) u16 As[128 * 64];
  __shared__ __align__(16) u16 Bs[2][128 * 64];
  const int nwg = NT * 512;
  int bid = blockIdx.x;
  int logical = (bid & 7) * (nwg >> 3) + (bid >> 3);  // XCD-chunked (nwg%8==0)
  int mt = logical / NT, nt = logical % NT;
  int m0 = mt * 128, n0 = nt * 128;
  int tid = threadIdx.x, lane = tid & 63, w = tid >> 6;
  int wm = w >> 1, wn = w & 1, rla = lane & 15, hi = lane >> 4;
  // B glds map: dest linear (base + lane*16), source pre-swizzled
  int grow = w * 8 + (lane >> 3);
  int gsg = (lane & 7) ^ (grow & 7);
  const u16* Bb = B + (bstr ? (long)(m0 >> 12) * bstr : 0) + (size_t)n0 * ldb;
  // A staging map: 2 threads/row, 32 elems each
  int arow = tid >> 1, ahalf = tid & 1;

  f32x4 acc[4][4];
#pragma unroll
  for (int i = 0; i < 4; ++i)
#pragma unroll
    for (int j = 0; j < 4; ++j) acc[i][j] = (f32x4){0.f, 0.f, 0.f, 0.f};

  f32x4 afr[8];   // fp32 A stage (AF32)
  short8 abr[4];  // bf16 A stage (!AF32)

  auto issueB = [&](int kt, int c) {
#pragma unroll
    for (int p = 0; p < 4; ++p) {
      int r = p * 32 + grow;
      glds16(Bb + (size_t)r * ldb + kt * 64 + gsg * 8, &Bs[c][r * 64 + (lane & 7) * 8]);
    }
  };
  auto loadA = [&](int kt) {
    if constexpr (AF32) {
      const float* p = Af + (size_t)(m0 + arow) * 256 + kt * 64 + ahalf * 32;
#pragma unroll
      for (int i = 0; i < 8; ++i) afr[i] = *(const f32x4*)(p + i * 4);
    } else {
      const u16* Ak; int ktl;
      if (DUAL && kt >= KT / 2) { Ak = A1; ktl = kt - KT / 2; }
      else { Ak = A0; ktl = kt; }
      const u16* p = Ak + (size_t)(m0 + arow) * 256 + ktl * 64 + ahalf * 32;
#pragma unroll
      for (int i = 0; i < 4; ++i) abr[i] = *(const short8*)(p + i * 8);
    }
  };
  auto writeA = [&]() {
#pragma unroll
    for (int i = 0; i < 4; ++i) {
      int g = ahalf * 4 + i;
      int off = arow * 64 + ((g ^ (arow & 7)) << 3);
      if constexpr (AF32) {
        short8 s; u16* sp = (u16*)&s;
        const float* f0 = (const float*)&afr[i * 2];
        const float* f1 = (const float*)&afr[i * 2 + 1];
#pragma unroll
        for (int e = 0; e < 4; ++e) { sp[e] = f2b(f0[e]); sp[4 + e] = f2b(f1[e]); }
        *(short8*)&As[off] = s;
      } else {
        *(short8*)&As[off] = abr[i];
      }
    }
  };

  // prologue: tile0 (B then A so A-wait drains B), tile1 in flight
  issueB(0, 0);
  loadA(0);
  __builtin_amdgcn_sched_barrier(0);
  writeA();                // compiler waits A(0) loads -> drains B(0) too
  issueB(1, 1);
  loadA(1);
  __builtin_amdgcn_sched_barrier(0);
  asm volatile("s_waitcnt lgkmcnt(0)" ::: "memory");
  __builtin_amdgcn_s_barrier();
  __builtin_amdgcn_sched_barrier(0);

#pragma unroll
  for (int t = 0; t < KT; ++t) {
    int c = t & 1;
#pragma unroll
    for (int kk = 0; kk < 2; ++kk) {
      short8 af[4], bf[4];
#pragma unroll
      for (int i = 0; i < 4; ++i) {
        int ra = wm * 64 + i * 16 + rla;
        int rb = wn * 64 + i * 16 + rla;
        af[i] = *(const short8*)&As[ra * 64 + (((kk << 2) + hi) ^ (ra & 7)) * 8];
        bf[i] = *(const short8*)&Bs[c][rb * 64 + (((kk << 2) + hi) ^ (rb & 7)) * 8];
      }
#pragma unroll
      for (int i = 0; i < 4; ++i)
#pragma unroll
        for (int j = 0; j < 4; ++j)
          acc[i][j] = __builtin_amdgcn_mfma_f32_16x16x32_bf16(af[i], bf[j], acc[i][j], 0, 0, 0);
    }
    __builtin_amdgcn_sched_barrier(0);
    __builtin_amdgcn_s_barrier();  // all waves done reading As / Bs[c]
    __builtin_amdgcn_sched_barrier(0);
    if (t + 1 < KT) {
      writeA();  // A(t+1) -> As; compiler's vmcnt wait also drains B(t+1)
      if (t + 2 < KT) { issueB(t + 2, c); loadA(t + 2); }
      __builtin_amdgcn_sched_barrier(0);
      asm volatile("s_waitcnt lgkmcnt(0)" ::: "memory");
      __builtin_amdgcn_s_barrier();
      __builtin_amdgcn_sched_barrier(0);
    }
  }

  // epilogue
#pragma unroll
  for (int i = 0; i < 4; ++i)
#pragma unroll
    for (int j = 0; j < 4; ++j) {
      int cg = n0 + wn * 64 + j * 16 + rla;
      float bb = bias[cg];
#pragma unroll
      for (int e = 0; e < 4; ++e) {
        int row = m0 + wm * 64 + i * 16 + hi * 4 + e;
        float vv = acc[i][j][e] + bb;
        if constexpr (OUTF) {
          outf[(size_t)row * 256 + cg] = vv;
        } else {
          u16* o = (cg & 256) ? out1 : out0;
          o[(size_t)row * 256 + (cg & 255)] = f2b(vv);
        }
      }
    }
}

// ---------------- score: s[n][h][l] = ((act ⊙ g) @ Wa + ba) * SCALE ----------------
template <bool GATE>
__global__ __launch_bounds__(256) void score_k(const u16* act, const float* gate,
                                               const float* Wa, const float* ba, float* sout) {
  __shared__ float Ws[256][8];
  __shared__ float gs[256];
  int tid = threadIdx.x;
  for (int i = tid; i < 2048; i += 256) ((float*)Ws)[i] = Wa[i];
  if (GATE) gs[tid] = gate[(blockIdx.x >> 5) * 256 + tid];
  __syncthreads();
  int wv = tid >> 6, lane = tid & 63;
  int rl = lane >> 2, qq = lane & 3;
  for (int r0 = wv * 16; r0 < 128; r0 += 64) {
    int row = blockIdx.x * 128 + r0 + rl;
    const u16* ap = act + (size_t)row * 256 + qq * 64;
    float acc[8] = {0, 0, 0, 0, 0, 0, 0, 0};
#pragma unroll
    for (int ch = 0; ch < 8; ++ch) {
      short8 v = *(const short8*)(ap + ch * 8);
#pragma unroll
      for (int e = 0; e < 8; ++e) {
        int c = qq * 64 + ch * 8 + e;
        float x = b2f(((u16*)&v)[e]);
        if (GATE) x *= gs[c];
#pragma unroll
        for (int h = 0; h < 8; ++h) acc[h] += x * Ws[c][h];
      }
    }
#pragma unroll
    for (int h = 0; h < 8; ++h) {
      acc[h] += __shfl_xor(acc[h], 1);
      acc[h] += __shfl_xor(acc[h], 2);
    }
    if (qq == 0) {
      int n = row >> 12, l = row & 4095;
#pragma unroll
      for (int h = 0; h < 8; ++h)
        sout[(((size_t)n * 8 + h) << 12) + l] = (acc[h] + ba[h]) * SCALE_C;
    }
  }
}

// ---------------- softmax over L + pooled[n][h*32+d] ----------------
__global__ __launch_bounds__(256) void pool_k(const float* score, const u16* act,
                                              float* pooled) {
  __shared__ float p[4096];
  __shared__ float red[8];
  __shared__ float wsum[4][32];
  int n = blockIdx.x >> 3, h = blockIdx.x & 7;
  const float* s = score + (size_t)blockIdx.x * 4096;
  int tid = threadIdx.x;
  float v[16];
  float lmax = -3.0e38f;
#pragma unroll
  for (int i = 0; i < 16; ++i) { v[i] = s[i * 256 + tid]; lmax = fmaxf(lmax, v[i]); }
  for (int o = 32; o; o >>= 1) lmax = fmaxf(lmax, __shfl_xor(lmax, o));
  if ((tid & 63) == 0) red[tid >> 6] = lmax;
  __syncthreads();
  float m = fmaxf(fmaxf(red[0], red[1]), fmaxf(red[2], red[3]));
  float lsum = 0.f;
#pragma unroll
  for (int i = 0; i < 16; ++i) { float e = __expf(v[i] - m); p[i * 256 + tid] = e; lsum += e; }
  for (int o = 32; o; o >>= 1) lsum += __shfl_xor(lsum, o);
  if ((tid & 63) == 0) red[4 + (tid >> 6)] = lsum;
  __syncthreads();
  float inv = 1.f / (red[4] + red[5] + red[6] + red[7]);
  float acc[32];
#pragma unroll
  for (int d = 0; d < 32; ++d) acc[d] = 0.f;
  const u16* ap = act + (size_t)(n * 4096) * 256 + h * 32;
  for (int it = 0; it < 16; ++it) {
    int row = it * 256 + tid;
    float wgt = p[row] * inv;
    const u16* rp = ap + (size_t)row * 256;
#pragma unroll
    for (int ch = 0; ch < 4; ++ch) {
      short8 x = *(const short8*)(rp + ch * 8);
#pragma unroll
      for (int e = 0; e < 8; ++e) acc[ch * 8 + e] += wgt * b2f(((u16*)&x)[e]);
    }
  }
#pragma unroll
  for (int d = 0; d < 32; ++d)
    for (int o = 32; o; o >>= 1) acc[d] += __shfl_xor(acc[d], o);
  __syncthreads();
  if ((tid & 63) == 0)
#pragma unroll
    for (int d = 0; d < 32; ++d) wsum[tid >> 6][d] = acc[d];
  __syncthreads();
  if (tid < 32)
    pooled[(n << 8) + h * 32 + tid] = wsum[0][tid] + wsum[1][tid] + wsum[2][tid] + wsum[3][tid];
}

// ---------------- launch ----------------
extern "C" void kernel_launch(void* const* d_in, const int* in_sizes, int n_in,
                              void* d_out, int out_size, void* d_ws, size_t ws_size,
                              hipStream_t stream) {
  const float* x_q = (const float*)d_in[0];
  const float* x_kv = (const float*)d_in[1];
  const float* Wq = (const float*)d_in[2];
  const float* bq = (const float*)d_in[3];
  const float* Wqa = (const float*)d_in[4];
  const float* bqa = (const float*)d_in[5];
  const float* Wk = (const float*)d_in[6];
  const float* bk = (const float*)d_in[7];
  const float* Wka = (const float*)d_in[8];
  const float* bka = (const float*)d_in[9];
  const float* Wv = (const float*)d_in[10];
  const float* bv = (const float*)d_in[11];
  const float* Wt = (const float*)d_in[12];
  const float* bt = (const float*)d_in[13];
  const float* Wo = (const float*)d_in[14];
  const float* bo = (const float*)d_in[15];

  char* w = (char*)d_ws;
  size_t off = 0;
  u16* q_ws = (u16*)(w + off); off += (size_t)65536 * 256 * 2;   // 32MB
  u16* k_ws = (u16*)(w + off); off += (size_t)65536 * 256 * 2;   // 32MB
  u16* v_ws = (u16*)(w + off); off += (size_t)65536 * 256 * 2;   // 32MB
  float* score = (float*)(w + off); off += (size_t)16 * 8 * 4096 * 4;  // 2MB shared q/k
  float* pq = (float*)(w + off); off += 16 * 256 * 4;
  float* pk = (float*)(w + off); off += 16 * 256 * 4;
  u16* wqT = (u16*)(w + off); off += 256 * 256 * 2;
  u16* wkvT = (u16*)(w + off); off += 512 * 256 * 2;
  u16* woT = (u16*)(w + off); off += 256 * 256 * 2;
  float* wtloT = (float*)(w + off); off += 256 * 256 * 4;
  float* btlo = (float*)(w + off); off += 256 * 4;
  float* bkv = (float*)(w + off); off += 512 * 4;
  u16* B5 = (u16*)(w + off); off += (size_t)16 * 256 * 512 * 2;  // 4MB
  if (ws_size < off) return;

  prep0<<<256, 256, 0, stream>>>(Wq, Wk, Wv, Wo, bk, bv, wqT, wkvT, woT, bkv);
  prep1<<<256, 256, 0, stream>>>(Wt, Wo, bt, bo, wtloT, btlo);

  // G1: q = x_q @ Wq + bq -> q_ws (bf16), fused fp32->bf16 A staging
  gemm4<4, true, false, false, 2><<<1024, 256, 0, stream>>>(
      x_q, nullptr, nullptr, wqT, 256, 0L, bq, q_ws, nullptr, nullptr);
  score_k<false><<<512, 256, 0, stream>>>(q_ws, nullptr, Wqa, bqa, score);
  pool_k<<<128, 256, 0, stream>>>(score, q_ws, pq);

  // G2: [k|v] = x_kv @ [Wk|Wv] + [bk|bv] -> k_ws, v_ws
  gemm4<4, true, false, false, 4><<<2048, 256, 0, stream>>>(
      x_kv, nullptr, nullptr, wkvT, 256, 0L, bkv, k_ws, v_ws, nullptr);
  score_k<true><<<512, 256, 0, stream>>>(k_ws, pq, Wka, bka, score);
  pool_k<<<128, 256, 0, stream>>>(score, k_ws, pk);

  // per-n B5 = [diag(pk)*Wtlo ; Wo]  ([n][j][512])
  prep2<<<16 * 256, 256, 0, stream>>>(pk, wtloT, woT, B5);

  // G3: out = v @ B5_lo + q @ Wo + btlo  (dual-A bf16, K=512, fp32 out)
  gemm4<8, false, true, true, 2><<<1024, 256, 0, stream>>>(
      nullptr, v_ws, q_ws, B5, 512, 131072L, btlo, nullptr, nullptr, (float*)d_out);
}

// Round 5
// 249.996 us; speedup vs baseline: 1.0561x; 1.0561x over previous
//
#include <hip/hip_runtime.h>
#include <hip/hip_bf16.h>

typedef short short8 __attribute__((ext_vector_type(8)));
typedef float f32x4 __attribute__((ext_vector_type(4)));
typedef unsigned short u16;

#define SCALE_C 0.17677669529663687f

__device__ __forceinline__ u16 f2b(float f) {
  union { float f; unsigned int u; } v; v.f = f;
  unsigned int u = v.u;
  return (u16)((u + 0x7FFFu + ((u >> 16) & 1u)) >> 16);
}
__device__ __forceinline__ float b2f(u16 b) {
  union { unsigned int u; float f; } v; v.u = ((unsigned int)b) << 16; return v.f;
}
__device__ __forceinline__ unsigned int cvtpk(float lo, float hi) {
  unsigned int r;
  asm("v_cvt_pk_bf16_f32 %0, %1, %2" : "=v"(r) : "v"(lo), "v"(hi));
  return r;
}
__device__ __forceinline__ void glds16(const void* g, void* l) {
  __builtin_amdgcn_global_load_lds(
      (const __attribute__((address_space(1))) unsigned int*)g,
      (__attribute__((address_space(3))) unsigned int*)l, 16, 0, 0);
}

// ---------------- prep kernels ----------------
__global__ void prep0(const float* Wq, const float* Wk, const float* Wv, const float* Wo,
                      const float* bk, const float* bv,
                      u16* wqT, u16* wkvT, u16* woT, float* bkv) {
  int j = blockIdx.x, t = threadIdx.x;
  wqT[j * 256 + t] = f2b(Wq[t * 256 + j]);
  wkvT[j * 256 + t] = f2b(Wk[t * 256 + j]);
  wkvT[(256 + j) * 256 + t] = f2b(Wv[t * 256 + j]);
  woT[j * 256 + t] = f2b(Wo[t * 256 + j]);
  if (t == 0) { bkv[j] = bk[j]; bkv[256 + j] = bv[j]; }
}

__global__ void prep1(const float* Wt, const float* Wo, const float* bt, const float* bo,
                      float* wtloT, float* btlo) {
  __shared__ float woj[256];
  int j = blockIdx.x, c = threadIdx.x;
  woj[c] = Wo[c * 256 + j];
  __syncthreads();
  float s = 0.f;
  const float* wr = Wt + c * 256;
#pragma unroll 8
  for (int t = 0; t < 256; ++t) s += wr[t] * woj[t];
  wtloT[j * 256 + c] = s;  // = Wtlo[c][j]
  if (c == 0) {
    float b = bo[j];
    for (int t = 0; t < 256; ++t) b += bt[t] * woj[t];
    btlo[j] = b;
  }
}

__global__ void prep2(const float* pk, const float* wtloT, const u16* woT, u16* B5) {
  int n = blockIdx.x >> 8, j = blockIdx.x & 255, t = threadIdx.x;
  u16* r = B5 + ((size_t)(n * 256 + j)) * 512;
  r[t] = f2b(pk[n * 256 + t] * wtloT[j * 256 + t]);
  r[256 + t] = woT[j * 256 + t];
}

// ---------------- GEMM: 128x128 tile, BK=128, 8 waves, 64KB LDS, 2 blk/CU --------
// LDS rows of 128 bf16 (256B = 16 granules of 16B). XOR-swizzle low 3 granule bits
// with (row&7); achieved on the write side via inverse-swizzled source addressing
// (global_load_lds dest stays linear), so write AND read are both ~2-way on banks.
template <int KT, bool AF32, bool DUAL, bool OUTF, int NT>
__global__ __launch_bounds__(512, 4) void gemm5(
    const float* Af, const u16* A0, const u16* A1, const u16* B, int ldb, long bstr,
    const float* bias, u16* out0, u16* out1, float* outf) {
  __shared__ __align__(16) u16 As[128 * 128];  // 32KB
  __shared__ __align__(16) u16 Bs[128 * 128];  // 32KB
  const int nwg = NT * 512;
  int bid = blockIdx.x;
  int logical = (bid & 7) * (nwg >> 3) + (bid >> 3);  // XCD-chunked (nwg%8==0)
  int mt = logical / NT, nt = logical % NT;
  int m0 = mt * 128, n0 = nt * 128;
  int tid = threadIdx.x, lane = tid & 63, w = tid >> 6;
  int wm = w >> 2, wn = w & 3;  // 2(M) x 4(N) wave grid; wave tile 64x32
  int rla = lane & 15, hi = lane >> 4;
  int srow = w * 4 + (lane >> 4);  // staging row within each 32-row group
  int gl = lane & 15;              // staging granule (16B)
  int gg = (gl & 8) | ((gl & 7) ^ (srow & 7));  // inverse-swizzled source granule
  const u16* Bb = B + (bstr ? (long)(m0 >> 12) * bstr : 0) + (size_t)n0 * ldb;

  f32x4 acc[4][2];
#pragma unroll
  for (int i = 0; i < 4; ++i)
#pragma unroll
    for (int j = 0; j < 2; ++j) acc[i][j] = (f32x4){0.f, 0.f, 0.f, 0.f};

  for (int kt = 0; kt < KT; ++kt) {
    // ---- stage B via global_load_lds (linear dest = wave base + lane*16) ----
#pragma unroll
    for (int p = 0; p < 4; ++p) {
      int r = p * 32 + srow;
      glds16(Bb + (size_t)r * ldb + kt * 128 + gg * 8,
             (char*)Bs + (p * 32 + w * 4) * 256 + lane * 16);
    }
    // ---- stage A ----
    if constexpr (AF32) {
#pragma unroll
      for (int p = 0; p < 4; ++p) {
        int r = p * 32 + srow;
        const float* s = Af + (size_t)(m0 + r) * 256 + kt * 128 + gg * 8;
        f32x4 x = *(const f32x4*)s;
        f32x4 y = *(const f32x4*)(s + 4);
        short8 o; unsigned int* op = (unsigned int*)&o;
        op[0] = cvtpk(x[0], x[1]); op[1] = cvtpk(x[2], x[3]);
        op[2] = cvtpk(y[0], y[1]); op[3] = cvtpk(y[2], y[3]);
        *(short8*)((char*)As + r * 256 + gl * 16) = o;
      }
    } else {
      const u16* Ak; int koff;
      if (DUAL && kt >= KT / 2) { Ak = A1; koff = (kt - KT / 2) * 128; }
      else { Ak = A0; koff = kt * 128; }
#pragma unroll
      for (int p = 0; p < 4; ++p) {
        int r = p * 32 + srow;
        glds16(Ak + (size_t)(m0 + r) * 256 + koff + gg * 8,
               (char*)As + (p * 32 + w * 4) * 256 + lane * 16);
      }
    }
    __syncthreads();  // drains vmcnt (glds) + lgkmcnt (ds_write)
    // ---- compute: 4 k-steps of 32 ----
#pragma unroll
    for (int ks = 0; ks < 4; ++ks) {
      int gd = ks * 4 + hi;
      short8 af[4], bf[2];
#pragma unroll
      for (int i = 0; i < 4; ++i) {
        int ra = wm * 64 + i * 16 + rla;
        int lg = (gd & 8) | ((gd & 7) ^ (ra & 7));
        af[i] = *(const short8*)((char*)As + ra * 256 + lg * 16);
      }
#pragma unroll
      for (int j = 0; j < 2; ++j) {
        int rb = wn * 32 + j * 16 + rla;
        int lg = (gd & 8) | ((gd & 7) ^ (rb & 7));
        bf[j] = *(const short8*)((char*)Bs + rb * 256 + lg * 16);
      }
#pragma unroll
      for (int i = 0; i < 4; ++i)
#pragma unroll
        for (int j = 0; j < 2; ++j)
          acc[i][j] = __builtin_amdgcn_mfma_f32_16x16x32_bf16(af[i], bf[j], acc[i][j], 0, 0, 0);
    }
    __syncthreads();
  }
  // ---- epilogue ----
#pragma unroll
  for (int i = 0; i < 4; ++i)
#pragma unroll
    for (int j = 0; j < 2; ++j) {
      int cg = n0 + wn * 32 + j * 16 + rla;
      float bb = bias[cg];
#pragma unroll
      for (int e = 0; e < 4; ++e) {
        int row = m0 + wm * 64 + i * 16 + hi * 4 + e;
        float vv = acc[i][j][e] + bb;
        if constexpr (OUTF) {
          outf[(size_t)row * 256 + cg] = vv;
        } else {
          u16* o = (cg & 256) ? out1 : out0;
          o[(size_t)row * 256 + (cg & 255)] = f2b(vv);
        }
      }
    }
}

// ---------------- score: s[n][h][l] = ((act ⊙ g) @ Wa + ba) * SCALE ----------------
template <bool GATE>
__global__ __launch_bounds__(256) void score_k(const u16* act, const float* gate,
                                               const float* Wa, const float* ba, float* sout) {
  __shared__ float Ws[256][8];
  __shared__ float gs[256];
  int tid = threadIdx.x;
  for (int i = tid; i < 2048; i += 256) ((float*)Ws)[i] = Wa[i];
  if (GATE) gs[tid] = gate[(blockIdx.x >> 5) * 256 + tid];
  __syncthreads();
  int wv = tid >> 6, lane = tid & 63;
  int rl = lane >> 2, qq = lane & 3;
  for (int r0 = wv * 16; r0 < 128; r0 += 64) {
    int row = blockIdx.x * 128 + r0 + rl;
    const u16* ap = act + (size_t)row * 256 + qq * 64;
    float acc[8] = {0, 0, 0, 0, 0, 0, 0, 0};
#pragma unroll
    for (int ch = 0; ch < 8; ++ch) {
      short8 v = *(const short8*)(ap + ch * 8);
#pragma unroll
      for (int e = 0; e < 8; ++e) {
        int c = qq * 64 + ch * 8 + e;
        float x = b2f(((u16*)&v)[e]);
        if (GATE) x *= gs[c];
#pragma unroll
        for (int h = 0; h < 8; ++h) acc[h] += x * Ws[c][h];
      }
    }
#pragma unroll
    for (int h = 0; h < 8; ++h) {
      acc[h] += __shfl_xor(acc[h], 1);
      acc[h] += __shfl_xor(acc[h], 2);
    }
    if (qq == 0) {
      int n = row >> 12, l = row & 4095;
#pragma unroll
      for (int h = 0; h < 8; ++h)
        sout[(((size_t)n * 8 + h) << 12) + l] = (acc[h] + ba[h]) * SCALE_C;
    }
  }
}

// ---------------- softmax over L + pooled[n][h*32+d] ----------------
__global__ __launch_bounds__(256) void pool_k(const float* score, const u16* act,
                                              float* pooled) {
  __shared__ float p[4096];
  __shared__ float red[8];
  __shared__ float wsum[4][32];
  int n = blockIdx.x >> 3, h = blockIdx.x & 7;
  const float* s = score + (size_t)blockIdx.x * 4096;
  int tid = threadIdx.x;
  float v[16];
  float lmax = -3.0e38f;
#pragma unroll
  for (int i = 0; i < 16; ++i) { v[i] = s[i * 256 + tid]; lmax = fmaxf(lmax, v[i]); }
  for (int o = 32; o; o >>= 1) lmax = fmaxf(lmax, __shfl_xor(lmax, o));
  if ((tid & 63) == 0) red[tid >> 6] = lmax;
  __syncthreads();
  float m = fmaxf(fmaxf(red[0], red[1]), fmaxf(red[2], red[3]));
  float lsum = 0.f;
#pragma unroll
  for (int i = 0; i < 16; ++i) { float e = __expf(v[i] - m); p[i * 256 + tid] = e; lsum += e; }
  for (int o = 32; o; o >>= 1) lsum += __shfl_xor(lsum, o);
  if ((tid & 63) == 0) red[4 + (tid >> 6)] = lsum;
  __syncthreads();
  float inv = 1.f / (red[4] + red[5] + red[6] + red[7]);
  float acc[32];
#pragma unroll
  for (int d = 0; d < 32; ++d) acc[d] = 0.f;
  const u16* ap = act + (size_t)(n * 4096) * 256 + h * 32;
  for (int it = 0; it < 16; ++it) {
    int row = it * 256 + tid;
    float wgt = p[row] * inv;
    const u16* rp = ap + (size_t)row * 256;
#pragma unroll
    for (int ch = 0; ch < 4; ++ch) {
      short8 x = *(const short8*)(rp + ch * 8);
#pragma unroll
      for (int e = 0; e < 8; ++e) acc[ch * 8 + e] += wgt * b2f(((u16*)&x)[e]);
    }
  }
#pragma unroll
  for (int d = 0; d < 32; ++d)
    for (int o = 32; o; o >>= 1) acc[d] += __shfl_xor(acc[d], o);
  __syncthreads();
  if ((tid & 63) == 0)
#pragma unroll
    for (int d = 0; d < 32; ++d) wsum[tid >> 6][d] = acc[d];
  __syncthreads();
  if (tid < 32)
    pooled[(n << 8) + h * 32 + tid] = wsum[0][tid] + wsum[1][tid] + wsum[2][tid] + wsum[3][tid];
}

// ---------------- launch ----------------
extern "C" void kernel_launch(void* const* d_in, const int* in_sizes, int n_in,
                              void* d_out, int out_size, void* d_ws, size_t ws_size,
                              hipStream_t stream) {
  const float* x_q = (const float*)d_in[0];
  const float* x_kv = (const float*)d_in[1];
  const float* Wq = (const float*)d_in[2];
  const float* bq = (const float*)d_in[3];
  const float* Wqa = (const float*)d_in[4];
  const float* bqa = (const float*)d_in[5];
  const float* Wk = (const float*)d_in[6];
  const float* bk = (const float*)d_in[7];
  const float* Wka = (const float*)d_in[8];
  const float* bka = (const float*)d_in[9];
  const float* Wv = (const float*)d_in[10];
  const float* bv = (const float*)d_in[11];
  const float* Wt = (const float*)d_in[12];
  const float* bt = (const float*)d_in[13];
  const float* Wo = (const float*)d_in[14];
  const float* bo = (const float*)d_in[15];

  char* w = (char*)d_ws;
  size_t off = 0;
  u16* q_ws = (u16*)(w + off); off += (size_t)65536 * 256 * 2;   // 32MB
  u16* k_ws = (u16*)(w + off); off += (size_t)65536 * 256 * 2;   // 32MB
  u16* v_ws = (u16*)(w + off); off += (size_t)65536 * 256 * 2;   // 32MB
  float* score = (float*)(w + off); off += (size_t)16 * 8 * 4096 * 4;  // 2MB shared q/k
  float* pq = (float*)(w + off); off += 16 * 256 * 4;
  float* pk = (float*)(w + off); off += 16 * 256 * 4;
  u16* wqT = (u16*)(w + off); off += 256 * 256 * 2;
  u16* wkvT = (u16*)(w + off); off += 512 * 256 * 2;
  u16* woT = (u16*)(w + off); off += 256 * 256 * 2;
  float* wtloT = (float*)(w + off); off += 256 * 256 * 4;
  float* btlo = (float*)(w + off); off += 256 * 4;
  float* bkv = (float*)(w + off); off += 512 * 4;
  u16* B5 = (u16*)(w + off); off += (size_t)16 * 256 * 512 * 2;  // 4MB
  if (ws_size < off) return;

  prep0<<<256, 256, 0, stream>>>(Wq, Wk, Wv, Wo, bk, bv, wqT, wkvT, woT, bkv);
  prep1<<<256, 256, 0, stream>>>(Wt, Wo, bt, bo, wtloT, btlo);

  // G1: q = x_q @ Wq + bq -> q_ws (bf16); fused fp32->bf16 A staging
  gemm5<2, true, false, false, 2><<<1024, 512, 0, stream>>>(
      x_q, nullptr, nullptr, wqT, 256, 0L, bq, q_ws, nullptr, nullptr);
  score_k<false><<<512, 256, 0, stream>>>(q_ws, nullptr, Wqa, bqa, score);
  pool_k<<<128, 256, 0, stream>>>(score, q_ws, pq);

  // G2: [k|v] = x_kv @ [Wk|Wv] + [bk|bv] -> k_ws, v_ws
  gemm5<2, true, false, false, 4><<<2048, 512, 0, stream>>>(
      x_kv, nullptr, nullptr, wkvT, 256, 0L, bkv, k_ws, v_ws, nullptr);
  score_k<true><<<512, 256, 0, stream>>>(k_ws, pq, Wka, bka, score);
  pool_k<<<128, 256, 0, stream>>>(score, k_ws, pk);

  // per-n B5 = [diag(pk)*Wtlo ; Wo]  ([n][j][512])
  prep2<<<16 * 256, 256, 0, stream>>>(pk, wtloT, woT, B5);

  // G3: out = v @ B5_lo + q @ Wo + btlo  (dual-A bf16, K=512, fp32 out)
  gemm5<4, false, true, true, 2><<<1024, 512, 0, stream>>>(
      nullptr, v_ws, q_ws, B5, 512, 131072L, btlo, nullptr, nullptr, (float*)d_out);
}

// Round 6
// 247.011 us; speedup vs baseline: 1.0688x; 1.0121x over previous
//
#include <hip/hip_runtime.h>
#include <hip/hip_bf16.h>

typedef short short8 __attribute__((ext_vector_type(8)));
typedef float f32x4 __attribute__((ext_vector_type(4)));
typedef unsigned short u16;

#define SCALE_C 0.17677669529663687f

__device__ __forceinline__ u16 f2b(float f) {
  union { float f; unsigned int u; } v; v.f = f;
  unsigned int u = v.u;
  return (u16)((u + 0x7FFFu + ((u >> 16) & 1u)) >> 16);
}
__device__ __forceinline__ float b2f(u16 b) {
  union { unsigned int u; float f; } v; v.u = ((unsigned int)b) << 16; return v.f;
}
__device__ __forceinline__ unsigned int cvtpk(float lo, float hi) {
  unsigned int r;
  asm("v_cvt_pk_bf16_f32 %0, %1, %2" : "=v"(r) : "v"(lo), "v"(hi));
  return r;
}
__device__ __forceinline__ void glds16(const void* g, void* l) {
  __builtin_amdgcn_global_load_lds(
      (const __attribute__((address_space(1))) unsigned int*)g,
      (__attribute__((address_space(3))) unsigned int*)l, 16, 0, 0);
}

// ---------------- prep kernels ----------------
__global__ void prep0(const float* Wq, const float* Wk, const float* Wv, const float* Wo,
                      const float* bk, const float* bv,
                      u16* wqT, u16* wkvT, u16* woT, float* bkv) {
  int j = blockIdx.x, t = threadIdx.x;
  wqT[j * 256 + t] = f2b(Wq[t * 256 + j]);
  wkvT[j * 256 + t] = f2b(Wk[t * 256 + j]);
  wkvT[(256 + j) * 256 + t] = f2b(Wv[t * 256 + j]);
  woT[j * 256 + t] = f2b(Wo[t * 256 + j]);
  if (t == 0) { bkv[j] = bk[j]; bkv[256 + j] = bv[j]; }
}

__global__ void prep1(const float* Wt, const float* Wo, const float* bt, const float* bo,
                      float* wtloT, float* btlo) {
  __shared__ float woj[256];
  int j = blockIdx.x, c = threadIdx.x;
  woj[c] = Wo[c * 256 + j];
  __syncthreads();
  float s = 0.f;
  const float* wr = Wt + c * 256;
#pragma unroll 8
  for (int t = 0; t < 256; ++t) s += wr[t] * woj[t];
  wtloT[j * 256 + c] = s;  // = Wtlo[c][j]
  if (c == 0) {
    float b = bo[j];
    for (int t = 0; t < 256; ++t) b += bt[t] * woj[t];
    btlo[j] = b;
  }
}

__global__ void prep2(const float* pk, const float* wtloT, const u16* woT, u16* B5) {
  int n = blockIdx.x >> 8, j = blockIdx.x & 255, t = threadIdx.x;
  u16* r = B5 + ((size_t)(n * 256 + j)) * 512;
  r[t] = f2b(pk[n * 256 + t] * wtloT[j * 256 + t]);
  r[256 + t] = woT[j * 256 + t];
}

// ---------------- GEMM: glds-only staging (round-3 skeleton) ----------------
// 128x128 tile, 4 waves (2x2), BK=64, 2-barrier loop.
// B (and bf16 A): LDS [128 rows][64 bf16] = 128B rows, 8 granules of 16B,
//   self-inverse XOR g^(row&7) done via pre-swizzled GLOBAL source (dest linear).
// fp32 A (AF32): LDS [128 rows][64 f32] = 256B rows, 16 granules,
//   XOR (g&8)|((g&7)^(row&7)); converted to bf16 on the LDS->frag read (cvt_pk).
template <int KT, bool AF32, bool DUAL, bool OUTF, int NT>
__global__ __launch_bounds__(256) void gemm6(
    const float* Af, const u16* A0, const u16* A1, const u16* B, int ldb, long bstr,
    const float* bias, u16* out0, u16* out1, float* outf) {
  constexpr int ABYTES = AF32 ? 32768 : 16384;
  __shared__ __align__(16) char smem[ABYTES + 16384];
  char* AsP = smem;
  char* BsP = smem + ABYTES;
  const int nwg = NT * 512;
  int bid = blockIdx.x;
  int logical = (bid & 7) * (nwg >> 3) + (bid >> 3);  // XCD-chunked (nwg%8==0)
  int mt = logical / NT, nt = logical % NT;
  int m0 = mt * 128, n0 = nt * 128;
  int tid = threadIdx.x, lane = tid & 63, w = tid >> 6;
  int wm = w >> 1, wn = w & 1, rla = lane & 15, hi = lane >> 4;
  // B staging map: 8 rows/wave-pass, 8x16B granules per 128B row
  int growB = w * 8 + (lane >> 3);
  int gsB = (lane & 7) ^ (growB & 7);
  // fp32 A staging map: 4 rows/wave-pass, 16x16B granules per 256B row
  int growA = w * 4 + (lane >> 4);
  int glA = lane & 15;
  int gsA = (glA & 8) | ((glA & 7) ^ (growA & 7));
  const u16* Bb = B + (bstr ? (long)(m0 >> 12) * bstr : 0) + (size_t)n0 * ldb;

  f32x4 acc[4][4];
#pragma unroll
  for (int i = 0; i < 4; ++i)
#pragma unroll
    for (int j = 0; j < 4; ++j) acc[i][j] = (f32x4){0.f, 0.f, 0.f, 0.f};

  for (int kt = 0; kt < KT; ++kt) {
    // ---- stage B ----
#pragma unroll
    for (int p = 0; p < 4; ++p) {
      int r = p * 32 + growB;
      glds16(Bb + (size_t)r * ldb + kt * 64 + gsB * 8,
             BsP + (p * 32 + w * 8) * 128 + lane * 16);
    }
    // ---- stage A ----
    if constexpr (AF32) {
#pragma unroll
      for (int p = 0; p < 8; ++p) {
        int r = p * 16 + growA;
        glds16(Af + (size_t)(m0 + r) * 256 + kt * 64 + gsA * 4,
               AsP + (p * 16 + w * 4) * 256 + lane * 16);
      }
    } else {
      const u16* Ak; int koff;
      if (DUAL && kt >= KT / 2) { Ak = A1; koff = (kt - KT / 2) * 64; }
      else { Ak = A0; koff = kt * 64; }
#pragma unroll
      for (int p = 0; p < 4; ++p) {
        int r = p * 32 + growB;
        glds16(Ak + (size_t)(m0 + r) * 256 + koff + gsB * 8,
               AsP + (p * 32 + w * 8) * 128 + lane * 16);
      }
    }
    __syncthreads();  // compiler drains vmcnt before barrier
    // ---- compute ----
#pragma unroll
    for (int kk = 0; kk < 2; ++kk) {
      short8 af[4], bf[4];
#pragma unroll
      for (int i = 0; i < 4; ++i) {
        int ra = wm * 64 + i * 16 + rla;
        if constexpr (AF32) {
          int g0 = kk * 8 + hi * 2;
          int l0 = (g0 & 8) | ((g0 & 7) ^ (ra & 7));
          int l1 = ((g0 + 1) & 8) | (((g0 + 1) & 7) ^ (ra & 7));
          f32x4 x = *(const f32x4*)(AsP + ra * 256 + l0 * 16);
          f32x4 y = *(const f32x4*)(AsP + ra * 256 + l1 * 16);
          unsigned int* op = (unsigned int*)&af[i];
          op[0] = cvtpk(x[0], x[1]); op[1] = cvtpk(x[2], x[3]);
          op[2] = cvtpk(y[0], y[1]); op[3] = cvtpk(y[2], y[3]);
        } else {
          int gd = kk * 4 + hi;
          af[i] = *(const short8*)(AsP + ra * 128 + ((gd ^ (ra & 7)) * 16));
        }
        int rb = wn * 64 + i * 16 + rla;
        int gd = kk * 4 + hi;
        bf[i] = *(const short8*)(BsP + rb * 128 + ((gd ^ (rb & 7)) * 16));
      }
#pragma unroll
      for (int i = 0; i < 4; ++i)
#pragma unroll
        for (int j = 0; j < 4; ++j)
          acc[i][j] = __builtin_amdgcn_mfma_f32_16x16x32_bf16(af[i], bf[j], acc[i][j], 0, 0, 0);
    }
    __syncthreads();
  }
  // ---- epilogue ----
#pragma unroll
  for (int i = 0; i < 4; ++i)
#pragma unroll
    for (int j = 0; j < 4; ++j) {
      int cg = n0 + wn * 64 + j * 16 + rla;
      float bb = bias[cg];
#pragma unroll
      for (int e = 0; e < 4; ++e) {
        int row = m0 + wm * 64 + i * 16 + hi * 4 + e;
        float vv = acc[i][j][e] + bb;
        if constexpr (OUTF) {
          outf[(size_t)row * 256 + cg] = vv;
        } else {
          u16* o = (cg & 256) ? out1 : out0;
          o[(size_t)row * 256 + (cg & 255)] = f2b(vv);
        }
      }
    }
}

// ---------------- score: s[n][h][l] = ((act ⊙ g) @ Wa + ba) * SCALE ----------------
template <bool GATE>
__global__ __launch_bounds__(256) void score_k(const u16* act, const float* gate,
                                               const float* Wa, const float* ba, float* sout) {
  __shared__ float Ws[256][8];
  __shared__ float gs[256];
  int tid = threadIdx.x;
  for (int i = tid; i < 2048; i += 256) ((float*)Ws)[i] = Wa[i];
  if (GATE) gs[tid] = gate[(blockIdx.x >> 5) * 256 + tid];
  __syncthreads();
  int wv = tid >> 6, lane = tid & 63;
  int rl = lane >> 2, qq = lane & 3;
  for (int r0 = wv * 16; r0 < 128; r0 += 64) {
    int row = blockIdx.x * 128 + r0 + rl;
    const u16* ap = act + (size_t)row * 256 + qq * 64;
    float acc[8] = {0, 0, 0, 0, 0, 0, 0, 0};
#pragma unroll
    for (int ch = 0; ch < 8; ++ch) {
      short8 v = *(const short8*)(ap + ch * 8);
#pragma unroll
      for (int e = 0; e < 8; ++e) {
        int c = qq * 64 + ch * 8 + e;
        float x = b2f(((u16*)&v)[e]);
        if (GATE) x *= gs[c];
#pragma unroll
        for (int h = 0; h < 8; ++h) acc[h] += x * Ws[c][h];
      }
    }
#pragma unroll
    for (int h = 0; h < 8; ++h) {
      acc[h] += __shfl_xor(acc[h], 1);
      acc[h] += __shfl_xor(acc[h], 2);
    }
    if (qq == 0) {
      int n = row >> 12, l = row & 4095;
#pragma unroll
      for (int h = 0; h < 8; ++h)
        sout[(((size_t)n * 8 + h) << 12) + l] = (acc[h] + ba[h]) * SCALE_C;
    }
  }
}

// ---------------- softmax over L + pooled[n][h*32+d] ----------------
__global__ __launch_bounds__(256) void pool_k(const float* score, const u16* act,
                                              float* pooled) {
  __shared__ float p[4096];
  __shared__ float red[8];
  __shared__ float wsum[4][32];
  int n = blockIdx.x >> 3, h = blockIdx.x & 7;
  const float* s = score + (size_t)blockIdx.x * 4096;
  int tid = threadIdx.x;
  float v[16];
  float lmax = -3.0e38f;
#pragma unroll
  for (int i = 0; i < 16; ++i) { v[i] = s[i * 256 + tid]; lmax = fmaxf(lmax, v[i]); }
  for (int o = 32; o; o >>= 1) lmax = fmaxf(lmax, __shfl_xor(lmax, o));
  if ((tid & 63) == 0) red[tid >> 6] = lmax;
  __syncthreads();
  float m = fmaxf(fmaxf(red[0], red[1]), fmaxf(red[2], red[3]));
  float lsum = 0.f;
#pragma unroll
  for (int i = 0; i < 16; ++i) { float e = __expf(v[i] - m); p[i * 256 + tid] = e; lsum += e; }
  for (int o = 32; o; o >>= 1) lsum += __shfl_xor(lsum, o);
  if ((tid & 63) == 0) red[4 + (tid >> 6)] = lsum;
  __syncthreads();
  float inv = 1.f / (red[4] + red[5] + red[6] + red[7]);
  float acc[32];
#pragma unroll
  for (int d = 0; d < 32; ++d) acc[d] = 0.f;
  const u16* ap = act + (size_t)(n * 4096) * 256 + h * 32;
  for (int it = 0; it < 16; ++it) {
    int row = it * 256 + tid;
    float wgt = p[row] * inv;
    const u16* rp = ap + (size_t)row * 256;
#pragma unroll
    for (int ch = 0; ch < 4; ++ch) {
      short8 x = *(const short8*)(rp + ch * 8);
#pragma unroll
      for (int e = 0; e < 8; ++e) acc[ch * 8 + e] += wgt * b2f(((u16*)&x)[e]);
    }
  }
#pragma unroll
  for (int d = 0; d < 32; ++d)
    for (int o = 32; o; o >>= 1) acc[d] += __shfl_xor(acc[d], o);
  __syncthreads();
  if ((tid & 63) == 0)
#pragma unroll
    for (int d = 0; d < 32; ++d) wsum[tid >> 6][d] = acc[d];
  __syncthreads();
  if (tid < 32)
    pooled[(n << 8) + h * 32 + tid] = wsum[0][tid] + wsum[1][tid] + wsum[2][tid] + wsum[3][tid];
}

// ---------------- launch ----------------
extern "C" void kernel_launch(void* const* d_in, const int* in_sizes, int n_in,
                              void* d_out, int out_size, void* d_ws, size_t ws_size,
                              hipStream_t stream) {
  const float* x_q = (const float*)d_in[0];
  const float* x_kv = (const float*)d_in[1];
  const float* Wq = (const float*)d_in[2];
  const float* bq = (const float*)d_in[3];
  const float* Wqa = (const float*)d_in[4];
  const float* bqa = (const float*)d_in[5];
  const float* Wk = (const float*)d_in[6];
  const float* bk = (const float*)d_in[7];
  const float* Wka = (const float*)d_in[8];
  const float* bka = (const float*)d_in[9];
  const float* Wv = (const float*)d_in[10];
  const float* bv = (const float*)d_in[11];
  const float* Wt = (const float*)d_in[12];
  const float* bt = (const float*)d_in[13];
  const float* Wo = (const float*)d_in[14];
  const float* bo = (const float*)d_in[15];

  char* w = (char*)d_ws;
  size_t off = 0;
  u16* q_ws = (u16*)(w + off); off += (size_t)65536 * 256 * 2;   // 32MB
  u16* k_ws = (u16*)(w + off); off += (size_t)65536 * 256 * 2;   // 32MB
  u16* v_ws = (u16*)(w + off); off += (size_t)65536 * 256 * 2;   // 32MB
  float* score = (float*)(w + off); off += (size_t)16 * 8 * 4096 * 4;  // 2MB shared q/k
  float* pq = (float*)(w + off); off += 16 * 256 * 4;
  float* pk = (float*)(w + off); off += 16 * 256 * 4;
  u16* wqT = (u16*)(w + off); off += 256 * 256 * 2;
  u16* wkvT = (u16*)(w + off); off += 512 * 256 * 2;
  u16* woT = (u16*)(w + off); off += 256 * 256 * 2;
  float* wtloT = (float*)(w + off); off += 256 * 256 * 4;
  float* btlo = (float*)(w + off); off += 256 * 4;
  float* bkv = (float*)(w + off); off += 512 * 4;
  u16* B5 = (u16*)(w + off); off += (size_t)16 * 256 * 512 * 2;  // 4MB
  if (ws_size < off) return;

  prep0<<<256, 256, 0, stream>>>(Wq, Wk, Wv, Wo, bk, bv, wqT, wkvT, woT, bkv);
  prep1<<<256, 256, 0, stream>>>(Wt, Wo, bt, bo, wtloT, btlo);

  // G1: q = x_q @ Wq + bq -> q_ws (bf16); A = fp32 in LDS, cvt on read
  gemm6<4, true, false, false, 2><<<1024, 256, 0, stream>>>(
      x_q, nullptr, nullptr, wqT, 256, 0L, bq, q_ws, nullptr, nullptr);
  score_k<false><<<512, 256, 0, stream>>>(q_ws, nullptr, Wqa, bqa, score);
  pool_k<<<128, 256, 0, stream>>>(score, q_ws, pq);

  // G2: [k|v] = x_kv @ [Wk|Wv] + [bk|bv] -> k_ws, v_ws
  gemm6<4, true, false, false, 4><<<2048, 256, 0, stream>>>(
      x_kv, nullptr, nullptr, wkvT, 256, 0L, bkv, k_ws, v_ws, nullptr);
  score_k<true><<<512, 256, 0, stream>>>(k_ws, pq, Wka, bka, score);
  pool_k<<<128, 256, 0, stream>>>(score, k_ws, pk);

  // per-n B5 = [diag(pk)*Wtlo ; Wo]  ([n][j][512])
  prep2<<<16 * 256, 256, 0, stream>>>(pk, wtloT, woT, B5);

  // G3: out = v @ B5_lo + q @ Wo + btlo  (dual-A bf16, K=512, fp32 out)
  gemm6<8, false, true, true, 2><<<1024, 256, 0, stream>>>(
      nullptr, v_ws, q_ws, B5, 512, 131072L, btlo, nullptr, nullptr, (float*)d_out);
}